// Round 1
// 969.989 us; speedup vs baseline: 1.4770x; 1.4770x over previous
//
#include <hip/hip_runtime.h>
#include <stdint.h>

// Problem constants (from reference): B=2, S=2048, V=32000, E=H=512, L=3
#define BB 2
#define SS 2048
#define VV 32000
#define HH 512
#define LL 3
#define ROWS (BB * SS)      // 4096
#define G3 (3 * HH)         // 1536

#define NCHUNK 64
#define CLEN (SS / NCHUNK)  // 32

typedef __attribute__((ext_vector_type(8))) __bf16 bf16x8;
typedef __attribute__((ext_vector_type(4))) float f32x4;

// float -> bf16 round-to-nearest-even (bit trick, avoids header dependency)
__device__ __forceinline__ unsigned short f2bf(float f) {
    union { float f; unsigned int u; } cv; cv.f = f;
    unsigned int u = cv.u;
    u += 0x7fffu + ((u >> 16) & 1u);
    return (unsigned short)(u >> 16);
}

// async global->LDS, 16B per lane. LDS dest is wave-uniform base + lane*16 (HW).
__device__ __forceinline__ void gl2lds16(const void* g, void* l) {
    __builtin_amdgcn_global_load_lds(
        (__attribute__((address_space(1))) void*)g,
        (__attribute__((address_space(3))) void*)l, 16, 0, 0);
}

// ---------------- embedding gather: x[row] = emb[ids[row]] ----------------
__global__ __launch_bounds__(256) void embed_k(const int* __restrict__ ids,
                                               const float* __restrict__ emb,
                                               float* __restrict__ x) {
    int idx = blockIdx.x * blockDim.x + threadIdx.x;   // over ROWS * (HH/4)
    int row = idx >> 7;            // HH/4 = 128 float4 per row
    int c4  = idx & 127;
    int id = ids[row];
    *(float4*)(x + (size_t)row * HH + c4 * 4) =
        *(const float4*)(emb + (size_t)id * HH + c4 * 4);
}

// ---------------- fp32 -> bf16 bulk convert ----------------
__global__ __launch_bounds__(256) void tobf16_k(const float* __restrict__ in,
                                                unsigned short* __restrict__ outp,
                                                int n4) {
    int i = blockIdx.x * blockDim.x + threadIdx.x;
    if (i >= n4) return;
    float4 v = *(const float4*)(in + (size_t)i * 4);
    unsigned short o[4] = { f2bf(v.x), f2bf(v.y), f2bf(v.z), f2bf(v.w) };
    *(uint2*)(outp + (size_t)i * 4) = *(uint2*)o;
}

// ---------------- LayerNorm over H=512, one wave per row, writes bf16 ------
__global__ __launch_bounds__(256) void ln_k(const float* __restrict__ x,
                                            const float* __restrict__ w,
                                            const float* __restrict__ b,
                                            unsigned short* __restrict__ xn) {
    int wid  = (blockIdx.x * blockDim.x + threadIdx.x) >> 6;  // global wave = row
    int lane = threadIdx.x & 63;
    if (wid >= ROWS) return;
    const float* xr = x + (size_t)wid * HH;
    float4 v0 = *(const float4*)(xr + lane * 8);
    float4 v1 = *(const float4*)(xr + lane * 8 + 4);
    float vs[8] = { v0.x, v0.y, v0.z, v0.w, v1.x, v1.y, v1.z, v1.w };
    float s = 0.f, q = 0.f;
#pragma unroll
    for (int j = 0; j < 8; j++) { s += vs[j]; q += vs[j] * vs[j]; }
#pragma unroll
    for (int off = 32; off; off >>= 1) {
        s += __shfl_xor(s, off);
        q += __shfl_xor(q, off);
    }
    float mean = s * (1.f / HH);
    float var  = q * (1.f / HH) - mean * mean;
    float r    = rsqrtf(var + 1e-5f);
    unsigned short o[8];
#pragma unroll
    for (int j = 0; j < 8; j++) {
        float wj = w[lane * 8 + j];
        float bj = b ? b[lane * 8 + j] : 0.f;
        o[j] = f2bf((vs[j] - mean) * r * wj + bj);
    }
    *(uint4*)(xn + (size_t)wid * HH + lane * 8) = *(uint4*)o;
}

// ---------------- bf16 MFMA GEMM: C(MxN) = A(MxK) * Bt(NxK)^T + bias -------
// m97 structure: 128x128 tile, BK=32, 4 waves (each 64x64 via 4x4 mfma 16x16x32),
// global_load_lds dwordx4 staging into LINEAR LDS [128][32] (layout matches the
// wave-uniform-base + lane*16 DMA exactly), zero in-loop address VALU.
// Epilogue: per-wave LDS transpose -> float4 stores (256B contiguous per row,
// full-line writes; kills the 2.75x write amplification of scalar stores).
#define BM 128
#define BN 128
#define BK 32
#define MT (ROWS / BM)      // 32 m-tiles, both GEMMs have M=4096
#define SCPAD 68            // epilogue staging row stride (floats); 272B, 16B-aligned

__global__ __launch_bounds__(256) void gemm_bt(const unsigned short* __restrict__ A,
                                               const unsigned short* __restrict__ Bt,
                                               const float* __restrict__ bias,
                                               float* __restrict__ C,
                                               int K, int ldc) {
    // 17408 B: staging needs 16384 (lA+lB), epilogue needs 4*16*SCPAD*4 = 17408
    __shared__ __align__(16) char smem[4 * 16 * SCPAD * 4];
    unsigned short* lA = (unsigned short*)smem;
    unsigned short* lB = lA + BM * BK;

    // XCD-aware bijective swizzle (nwg % 8 == 0 for both call sites).
    // m-fastest: each XCD's contiguous chunk reuses its B-panel in private L2.
    int nwg = gridDim.x;
    int wg = blockIdx.x;
    if ((nwg & 7) == 0) { int q = nwg >> 3; wg = (wg & 7) * q + (wg >> 3); }
    int m0 = (wg % MT) * BM;
    int n0 = (wg / MT) * BN;

    int t = threadIdx.x;
    int lane = t & 63;
    int w = t >> 6;
    int wm = (w >> 1) * 64, wn = (w & 1) * 64;

    f32x4 acc[4][4];
#pragma unroll
    for (int i = 0; i < 4; i++)
#pragma unroll
        for (int j = 0; j < 4; j++) acc[i][j] = (f32x4){0.f, 0.f, 0.f, 0.f};

    // staging: idx = seg*256 + t; row = idx>>2, col-elem = (idx&3)*8 (16B/lane).
    // LDS byte offset = idx*16 == (seg*256 + w*64)*16 [wave-uniform] + lane*16.
    int r0 = t >> 2, c0 = (t & 3) * 8;
    const unsigned short* pa0 = A  + (size_t)(m0 + r0) * K + c0;
    const unsigned short* pa1 = A  + (size_t)(m0 + r0 + 64) * K + c0;
    const unsigned short* pb0 = Bt + (size_t)(n0 + r0) * K + c0;
    const unsigned short* pb1 = Bt + (size_t)(n0 + r0 + 64) * K + c0;
    unsigned short* dA0 = lA + (w * 64) * 8;
    unsigned short* dA1 = lA + (256 + w * 64) * 8;
    unsigned short* dB0 = lB + (w * 64) * 8;
    unsigned short* dB1 = lB + (256 + w * 64) * 8;

    // fragment read pointers (loop-invariant; rows are 64B in linear [128][32])
    int fm = lane & 15;
    int fq = (lane >> 4) * 8;
    const unsigned short* paf = lA + (wm + fm) * BK + fq;
    const unsigned short* pbf = lB + (wn + fm) * BK + fq;

    int nkt = K / BK;
    for (int kt = 0; kt < nkt; kt++) {
        gl2lds16(pa0, dA0);
        gl2lds16(pa1, dA1);
        gl2lds16(pb0, dB0);
        gl2lds16(pb1, dB1);
        pa0 += BK; pa1 += BK; pb0 += BK; pb1 += BK;
        __syncthreads();   // drains vmcnt -> LDS tile ready for all waves
        bf16x8 af[4], bfr[4];
#pragma unroll
        for (int i = 0; i < 4; i++) af[i] = *(const bf16x8*)(paf + i * 16 * BK);
#pragma unroll
        for (int j = 0; j < 4; j++) bfr[j] = *(const bf16x8*)(pbf + j * 16 * BK);
#pragma unroll
        for (int i = 0; i < 4; i++)
#pragma unroll
            for (int j = 0; j < 4; j++)
                acc[i][j] = __builtin_amdgcn_mfma_f32_16x16x32_bf16(
                    af[i], bfr[j], acc[i][j], 0, 0, 0);
        __syncthreads();   // all fragment reads done before next DMA overwrites
    }

    // ---- epilogue: wave-private LDS transpose, then coalesced float4 stores ----
    // C/D layout: col = lane&15, row = (lane>>4)*4 + reg (verified mapping).
    float* sc = (float*)(smem + w * 16 * SCPAD * 4);   // 4352B per wave, disjoint
    int cl = lane & 15, qh = lane >> 4;
    int gcol = n0 + wn + cl * 4;
    float4 bb = bias ? *(const float4*)(bias + gcol)
                     : make_float4(0.f, 0.f, 0.f, 0.f);
#pragma unroll
    for (int i = 0; i < 4; i++) {
        // scatter 16x64 slice into LDS (stride 68: qh-groups 2-way = free)
#pragma unroll
        for (int j = 0; j < 4; j++)
#pragma unroll
            for (int r = 0; r < 4; r++)
                sc[(qh * 4 + r) * SCPAD + j * 16 + cl] = acc[i][j][r];
        // read back row-major: 16 lanes cover 256B contiguous per row
#pragma unroll
        for (int rr = 0; rr < 4; rr++) {
            int lrow = rr * 4 + qh;
            float4 v = *(float4*)(sc + lrow * SCPAD + cl * 4);
            v.x += bb.x; v.y += bb.y; v.z += bb.z; v.w += bb.w;
            *(float4*)(C + (size_t)(m0 + wm + i * 16 + lrow) * ldc + gcol) = v;
        }
    }
}

// ---------------- scan phase 1: gate math + per-chunk affine summary -------
// thread tid: ch = tid&1023 (= b*H+h), c = tid>>10 (chunk). Rewrites gates
// in place: slot0 <- f' (forget), slot1 <- v = i'*g(tilde).
__global__ __launch_bounds__(256) void scan1_k(float* __restrict__ gates,
                                               float* __restrict__ Ach,
                                               float* __restrict__ Bch) {
    int tid = blockIdx.x * blockDim.x + threadIdx.x;
    int ch = tid & (BB * HH - 1);
    int c  = tid >> 10;
    int b = ch >> 9, h = ch & (HH - 1);
    float a = 1.f, acc = 0.f;
    size_t base = ((size_t)b * SS + (size_t)c * CLEN) * G3 + h;
    for (int s = 0; s < CLEN; s++) {
        float fg = gates[base];
        float ig = gates[base + HH];
        float tg = gates[base + 2 * HH];
        float sf = 1.f / (1.f + expf(-fg));
        float si = 1.f / (1.f + expf(-ig));
        float inv = 1.f / (sf + si);
        float fp = sf * inv;                       // f' = sig(f)/(sig(f)+sig(i))
        float ip = si * inv;
        float g  = tg >= 0.f ? tg + 0.5f : 1.f / (1.f + expf(-tg));
        float v  = ip * g;
        gates[base] = fp;
        gates[base + HH] = v;
        a = fp * a;
        acc = fp * acc + v;                        // compose h -> fp*h + v
        base += G3;
    }
    Ach[tid] = a;
    Bch[tid] = acc;
}

// ---------------- scan phase 2: scan across chunk summaries ---------------
__global__ __launch_bounds__(256) void scan2_k(const float* __restrict__ Ach,
                                               const float* __restrict__ Bch,
                                               float* __restrict__ hin) {
    int ch = blockIdx.x * blockDim.x + threadIdx.x;  // 1024 channels
    float hh = 0.5f;                                  // h0 = g(0) = 0.5
    for (int c = 0; c < NCHUNK; c++) {
        int i = c * (BB * HH) + ch;
        hin[i] = hh;                                  // h entering chunk c
        hh = Ach[i] * hh + Bch[i];
    }
}

// ---------------- scan phase 3: replay chunk, x += h (residual fused) ------
__global__ __launch_bounds__(256) void scan3_k(const float* __restrict__ gates,
                                               const float* __restrict__ hin,
                                               float* __restrict__ x) {
    int tid = blockIdx.x * blockDim.x + threadIdx.x;
    int ch = tid & (BB * HH - 1);
    int c  = tid >> 10;
    int b = ch >> 9, h = ch & (HH - 1);
    float hh = hin[c * (BB * HH) + ch];
    size_t gbase = ((size_t)b * SS + (size_t)c * CLEN) * G3 + h;
    size_t xbase = ((size_t)b * SS + (size_t)c * CLEN) * HH + h;
    for (int s = 0; s < CLEN; s++) {
        float fp = gates[gbase];
        float v  = gates[gbase + HH];
        hh = fp * hh + v;
        x[xbase] += hh;                               // x = inp + h
        gbase += G3;
        xbase += HH;
    }
}

extern "C" void kernel_launch(void* const* d_in, const int* in_sizes, int n_in,
                              void* d_out, int out_size, void* d_ws, size_t ws_size,
                              hipStream_t stream) {
    const int*   ids  = (const int*)  d_in[0];
    const float* emb  = (const float*)d_in[1];
    const float* Ws   = (const float*)d_in[2];
    const float* bs   = (const float*)d_in[3];
    const float* lnw  = (const float*)d_in[4];
    const float* lnb  = (const float*)d_in[5];
    const float* flnw = (const float*)d_in[6];
    const float* fcw  = (const float*)d_in[7];
    const float* fcb  = (const float*)d_in[8];
    float* out = (float*)d_out;

    // workspace layout (~76 MB total)
    char* p = (char*)d_ws;
    float* x            = (float*)p;           p += (size_t)ROWS * HH * 4;        // 8 MB
    unsigned short* xnb = (unsigned short*)p;  p += (size_t)ROWS * HH * 2;        // 4 MB
    unsigned short* wsb = (unsigned short*)p;  p += (size_t)LL * G3 * HH * 2;     // 4.7 MB
    unsigned short* fwb = (unsigned short*)p;  p += (size_t)VV * HH * 2;          // 32.8 MB
    float* gates        = (float*)p;           p += (size_t)ROWS * G3 * 4;        // 25 MB
    float* Ach          = (float*)p;           p += (size_t)NCHUNK * BB * HH * 4; // 256 KB
    float* Bch          = (float*)p;           p += (size_t)NCHUNK * BB * HH * 4;
    float* hin          = (float*)p;           p += (size_t)NCHUNK * BB * HH * 4;

    embed_k<<<ROWS * (HH / 4) / 256, 256, 0, stream>>>(ids, emb, x);
    tobf16_k<<<(LL * G3 * HH / 4 + 255) / 256, 256, 0, stream>>>(Ws, wsb, LL * G3 * HH / 4);
    tobf16_k<<<(VV * HH / 4 + 255) / 256, 256, 0, stream>>>(fcw, fwb, VV * HH / 4);

    for (int l = 0; l < LL; l++) {
        ln_k<<<ROWS / 4, 256, 0, stream>>>(x, lnw + l * HH, lnb + l * HH, xnb);
        gemm_bt<<<MT * (G3 / BN), 256, 0, stream>>>(
            xnb, wsb + (size_t)l * G3 * HH, bs + l * G3, gates, HH, G3);
        scan1_k<<<NCHUNK * BB * HH / 256, 256, 0, stream>>>(gates, Ach, Bch);
        scan2_k<<<BB * HH / 256, 256, 0, stream>>>(Ach, Bch, hin);
        scan3_k<<<NCHUNK * BB * HH / 256, 256, 0, stream>>>(gates, hin, x);
    }

    ln_k<<<ROWS / 4, 256, 0, stream>>>(x, flnw, nullptr, xnb);
    gemm_bt<<<MT * (VV / BN), 256, 0, stream>>>(xnb, fwb, fcb, out, HH, VV);
}

// Round 2
// 931.625 us; speedup vs baseline: 1.5378x; 1.0412x over previous
//
#include <hip/hip_runtime.h>
#include <stdint.h>

// Problem constants (from reference): B=2, S=2048, V=32000, E=H=512, L=3
#define BB 2
#define SS 2048
#define VV 32000
#define HH 512
#define LL 3
#define ROWS (BB * SS)      // 4096
#define G3 (3 * HH)         // 1536

#define NCHUNK 64
#define CLEN (SS / NCHUNK)  // 32

typedef __attribute__((ext_vector_type(8))) __bf16 bf16x8;
typedef __attribute__((ext_vector_type(4))) float f32x4;

// float -> bf16 round-to-nearest-even (bit trick, avoids header dependency)
__device__ __forceinline__ unsigned short f2bf(float f) {
    union { float f; unsigned int u; } cv; cv.f = f;
    unsigned int u = cv.u;
    u += 0x7fffu + ((u >> 16) & 1u);
    return (unsigned short)(u >> 16);
}

// async global->LDS, 16B per lane. LDS dest is wave-uniform base + lane*16 (HW).
__device__ __forceinline__ void gl2lds16(const void* g, void* l) {
    __builtin_amdgcn_global_load_lds(
        (__attribute__((address_space(1))) void*)g,
        (__attribute__((address_space(3))) void*)l, 16, 0, 0);
}

// ---------------- embedding gather: x[row] = emb[ids[row]] ----------------
__global__ __launch_bounds__(256) void embed_k(const int* __restrict__ ids,
                                               const float* __restrict__ emb,
                                               float* __restrict__ x) {
    int idx = blockIdx.x * blockDim.x + threadIdx.x;   // over ROWS * (HH/4)
    int row = idx >> 7;            // HH/4 = 128 float4 per row
    int c4  = idx & 127;
    int id = ids[row];
    *(float4*)(x + (size_t)row * HH + c4 * 4) =
        *(const float4*)(emb + (size_t)id * HH + c4 * 4);
}

// ---------------- fp32 -> bf16 bulk convert ----------------
__global__ __launch_bounds__(256) void tobf16_k(const float* __restrict__ in,
                                                unsigned short* __restrict__ outp,
                                                int n4) {
    int i = blockIdx.x * blockDim.x + threadIdx.x;
    if (i >= n4) return;
    float4 v = *(const float4*)(in + (size_t)i * 4);
    unsigned short o[4] = { f2bf(v.x), f2bf(v.y), f2bf(v.z), f2bf(v.w) };
    *(uint2*)(outp + (size_t)i * 4) = *(uint2*)o;
}

// ---------------- LayerNorm over H=512, one wave per row, writes bf16 ------
__global__ __launch_bounds__(256) void ln_k(const float* __restrict__ x,
                                            const float* __restrict__ w,
                                            const float* __restrict__ b,
                                            unsigned short* __restrict__ xn) {
    int wid  = (blockIdx.x * blockDim.x + threadIdx.x) >> 6;  // global wave = row
    int lane = threadIdx.x & 63;
    if (wid >= ROWS) return;
    const float* xr = x + (size_t)wid * HH;
    float4 v0 = *(const float4*)(xr + lane * 8);
    float4 v1 = *(const float4*)(xr + lane * 8 + 4);
    float vs[8] = { v0.x, v0.y, v0.z, v0.w, v1.x, v1.y, v1.z, v1.w };
    float s = 0.f, q = 0.f;
#pragma unroll
    for (int j = 0; j < 8; j++) { s += vs[j]; q += vs[j] * vs[j]; }
#pragma unroll
    for (int off = 32; off; off >>= 1) {
        s += __shfl_xor(s, off);
        q += __shfl_xor(q, off);
    }
    float mean = s * (1.f / HH);
    float var  = q * (1.f / HH) - mean * mean;
    float r    = rsqrtf(var + 1e-5f);
    unsigned short o[8];
#pragma unroll
    for (int j = 0; j < 8; j++) {
        float wj = w[lane * 8 + j];
        float bj = b ? b[lane * 8 + j] : 0.f;
        o[j] = f2bf((vs[j] - mean) * r * wj + bj);
    }
    *(uint4*)(xn + (size_t)wid * HH + lane * 8) = *(uint4*)o;
}

// ---------------- 128x128 bf16 MFMA GEMM (m97 structure) — layer GEMMs -----
#define BM 128
#define BN 128
#define BK 32
#define MT (ROWS / BM)      // 32 m-tiles
#define SCPAD 68            // epilogue staging row stride (floats)

__global__ __launch_bounds__(256) void gemm_bt(const unsigned short* __restrict__ A,
                                               const unsigned short* __restrict__ Bt,
                                               const float* __restrict__ bias,
                                               float* __restrict__ C,
                                               int K, int ldc) {
    __shared__ __align__(16) char smem[4 * 16 * SCPAD * 4];
    unsigned short* lA = (unsigned short*)smem;
    unsigned short* lB = lA + BM * BK;

    int nwg = gridDim.x;
    int wg = blockIdx.x;
    if ((nwg & 7) == 0) { int q = nwg >> 3; wg = (wg & 7) * q + (wg >> 3); }
    int m0 = (wg % MT) * BM;
    int n0 = (wg / MT) * BN;

    int t = threadIdx.x;
    int lane = t & 63;
    int w = t >> 6;
    int wm = (w >> 1) * 64, wn = (w & 1) * 64;

    f32x4 acc[4][4];
#pragma unroll
    for (int i = 0; i < 4; i++)
#pragma unroll
        for (int j = 0; j < 4; j++) acc[i][j] = (f32x4){0.f, 0.f, 0.f, 0.f};

    int r0 = t >> 2, c0 = (t & 3) * 8;
    const unsigned short* pa0 = A  + (size_t)(m0 + r0) * K + c0;
    const unsigned short* pa1 = A  + (size_t)(m0 + r0 + 64) * K + c0;
    const unsigned short* pb0 = Bt + (size_t)(n0 + r0) * K + c0;
    const unsigned short* pb1 = Bt + (size_t)(n0 + r0 + 64) * K + c0;
    unsigned short* dA0 = lA + (w * 64) * 8;
    unsigned short* dA1 = lA + (256 + w * 64) * 8;
    unsigned short* dB0 = lB + (w * 64) * 8;
    unsigned short* dB1 = lB + (256 + w * 64) * 8;

    int fm = lane & 15;
    int fq = (lane >> 4) * 8;
    const unsigned short* paf = lA + (wm + fm) * BK + fq;
    const unsigned short* pbf = lB + (wn + fm) * BK + fq;

    int nkt = K / BK;
    for (int kt = 0; kt < nkt; kt++) {
        gl2lds16(pa0, dA0);
        gl2lds16(pa1, dA1);
        gl2lds16(pb0, dB0);
        gl2lds16(pb1, dB1);
        pa0 += BK; pa1 += BK; pb0 += BK; pb1 += BK;
        __syncthreads();
        bf16x8 af[4], bfr[4];
#pragma unroll
        for (int i = 0; i < 4; i++) af[i] = *(const bf16x8*)(paf + i * 16 * BK);
#pragma unroll
        for (int j = 0; j < 4; j++) bfr[j] = *(const bf16x8*)(pbf + j * 16 * BK);
#pragma unroll
        for (int i = 0; i < 4; i++)
#pragma unroll
            for (int j = 0; j < 4; j++)
                acc[i][j] = __builtin_amdgcn_mfma_f32_16x16x32_bf16(
                    af[i], bfr[j], acc[i][j], 0, 0, 0);
        __syncthreads();
    }

    float* sc = (float*)(smem + w * 16 * SCPAD * 4);
    int cl = lane & 15, qh = lane >> 4;
    int gcol = n0 + wn + cl * 4;
    float4 bb = bias ? *(const float4*)(bias + gcol)
                     : make_float4(0.f, 0.f, 0.f, 0.f);
#pragma unroll
    for (int i = 0; i < 4; i++) {
#pragma unroll
        for (int j = 0; j < 4; j++)
#pragma unroll
            for (int r = 0; r < 4; r++)
                sc[(qh * 4 + r) * SCPAD + j * 16 + cl] = acc[i][j][r];
#pragma unroll
        for (int rr = 0; rr < 4; rr++) {
            int lrow = rr * 4 + qh;
            float4 v = *(float4*)(sc + lrow * SCPAD + cl * 4);
            v.x += bb.x; v.y += bb.y; v.z += bb.z; v.w += bb.w;
            *(float4*)(C + (size_t)(m0 + wm + i * 16 + lrow) * ldc + gcol) = v;
        }
    }
}

// ================== 256x256 8-phase bf16 GEMM (K=512 fixed) ================
// T3+T4 (8-phase counted vmcnt) + T2 (st_16x32 swizzle) + T5 (setprio).
// 8 waves (2M x 4N), per-wave output 128x64. BK=64 split into kk-halves of 32.
// LDS 128KB: [buf][mat][kk] 16KB regions, double-buffered by K-tile parity.
// Stage schedule per tile t: ph0:A1(t+1) ph1:B1(t+1) ph2:A0(t+2) ph3:B0(t+2);
// waits vmcnt(8) at ph1/ph3 (steady), drain 8->4->0 in epilogue. Each region
// is staged only after its last reader phase's end-barrier (race-free), and
// each half-tile is vmcnt-confirmed one phase before first read, ahead of a
// barrier (cross-wave visibility).
#define REGION(buf, mat, kk) ((((buf) * 2 + (mat)) * 2 + (kk)) * 16384)
#define WAITVM(n) asm volatile("s_waitcnt vmcnt(" #n ")" ::: "memory")

#define STAGE(tt, mat, kk) do { \
    char* d_ = smem + REGION((tt) & 1, mat, kk) + w * 2048; \
    const unsigned short* s0_ = (mat ? gB0 : gA0) + (tt) * 64 + (kk) * 32; \
    const unsigned short* s1_ = (mat ? gB1 : gA1) + (tt) * 64 + (kk) * 32; \
    gl2lds16(s0_, d_); \
    gl2lds16(s1_, d_ + 1024); \
} while (0)

#define MFMA4(OH, i4, av) do { \
    acc[(OH)*4+(i4)][0] = __builtin_amdgcn_mfma_f32_16x16x32_bf16(av, bq0, acc[(OH)*4+(i4)][0], 0, 0, 0); \
    acc[(OH)*4+(i4)][1] = __builtin_amdgcn_mfma_f32_16x16x32_bf16(av, bq1, acc[(OH)*4+(i4)][1], 0, 0, 0); \
    acc[(OH)*4+(i4)][2] = __builtin_amdgcn_mfma_f32_16x16x32_bf16(av, bq2, acc[(OH)*4+(i4)][2], 0, 0, 0); \
    acc[(OH)*4+(i4)][3] = __builtin_amdgcn_mfma_f32_16x16x32_bf16(av, bq3, acc[(OH)*4+(i4)][3], 0, 0, 0); \
} while (0)

#define PHASE(T, KK, OH, READB, STAGE_STMT, WAIT_STMT) do { \
    const char* Ab_ = smem + REGION((T) & 1, 0, KK) + aoff; \
    const char* Bb_ = smem + REGION((T) & 1, 1, KK) + boff; \
    bf16x8 a0_ = *(const bf16x8*)(Ab_ + ((OH)*4 + 0) * 1024); \
    bf16x8 a1_ = *(const bf16x8*)(Ab_ + ((OH)*4 + 1) * 1024); \
    bf16x8 a2_ = *(const bf16x8*)(Ab_ + ((OH)*4 + 2) * 1024); \
    bf16x8 a3_ = *(const bf16x8*)(Ab_ + ((OH)*4 + 3) * 1024); \
    if (READB) { \
        bq0 = *(const bf16x8*)(Bb_ + 0 * 1024); \
        bq1 = *(const bf16x8*)(Bb_ + 1 * 1024); \
        bq2 = *(const bf16x8*)(Bb_ + 2 * 1024); \
        bq3 = *(const bf16x8*)(Bb_ + 3 * 1024); \
    } \
    STAGE_STMT; \
    WAIT_STMT; \
    __builtin_amdgcn_sched_barrier(0); \
    __builtin_amdgcn_s_barrier(); \
    asm volatile("s_waitcnt lgkmcnt(0)" ::: "memory"); \
    __builtin_amdgcn_sched_barrier(0); \
    __builtin_amdgcn_s_setprio(1); \
    MFMA4(OH, 0, a0_); MFMA4(OH, 1, a1_); MFMA4(OH, 2, a2_); MFMA4(OH, 3, a3_); \
    __builtin_amdgcn_s_setprio(0); \
    __builtin_amdgcn_sched_barrier(0); \
    __builtin_amdgcn_s_barrier(); \
} while (0)

__global__ __launch_bounds__(512, 2) void gemm256(const unsigned short* __restrict__ A,
                                                  const unsigned short* __restrict__ Bt,
                                                  const float* __restrict__ bias,
                                                  float* __restrict__ C, int ldc) {
    __shared__ __align__(16) char smem[131072];

    int nwg = gridDim.x;
    int wg = blockIdx.x;
    if ((nwg & 7) == 0) { int q = nwg >> 3; wg = (wg & 7) * q + (wg >> 3); }
    int m0 = (wg & 15) * 256;          // M = 4096 -> 16 m-tiles, m-fastest
    int n0 = (wg >> 4) * 256;

    int tid = threadIdx.x;
    int lane = tid & 63;
    int w = tid >> 6;
    int wave_m = w >> 2, wave_n = w & 3;

    // fragment lane offset with st_16x32 read swizzle: swz bit = (row>>3)&1 = (fm>>3)&1
    int fm = lane & 15;
    int fq16 = (lane >> 4) * 16;                      // k-offset bytes within 64B row
    int lsw = (fm * 64 + fq16) ^ ((fm & 8) ? 32 : 0);
    int aoff = wave_m * 8192 + lsw;
    int boff = wave_n * 4096 + lsw;

    // staging source pre-swizzle: LDS dest is linear (base + lane*16); source picks
    // the element whose swizzled position is this lane's slot. swz bit = (lane>>5)&1.
    int ep = (lane * 8) ^ ((lane & 32) ? 16 : 0);     // element idx within 512-elem sweep
    int row_l = ep >> 5, kc_l = ep & 31;
    const unsigned short* gA0 = A  + (size_t)(m0 + w * 32 + row_l) * 512 + kc_l;
    const unsigned short* gA1 = gA0 + 16 * 512;
    const unsigned short* gB0 = Bt + (size_t)(n0 + w * 32 + row_l) * 512 + kc_l;
    const unsigned short* gB1 = gB0 + 16 * 512;

    f32x4 acc[8][4];
#pragma unroll
    for (int i = 0; i < 8; i++)
#pragma unroll
        for (int j = 0; j < 4; j++) acc[i][j] = (f32x4){0.f, 0.f, 0.f, 0.f};
    bf16x8 bq0, bq1, bq2, bq3;

    // prologue: stage A0(0) B0(0) A1(0) B1(0) A0(1) B0(1); confirm oldest 2 half-tiles
    STAGE(0, 0, 0); STAGE(0, 1, 0); STAGE(0, 0, 1); STAGE(0, 1, 1);
    STAGE(1, 0, 0); STAGE(1, 1, 0);
    WAITVM(8);
    __builtin_amdgcn_sched_barrier(0);
    __builtin_amdgcn_s_barrier();

#pragma unroll
    for (int t = 0; t < 8; ++t) {
        PHASE(t, 0, 0, 1,
              if (t < 7) STAGE(t + 1, 0, 1),
              (void)0);
        PHASE(t, 0, 1, 0,
              if (t < 7) STAGE(t + 1, 1, 1),
              if (t < 7) { WAITVM(8); } else { WAITVM(0); });
        PHASE(t, 1, 0, 1,
              if (t < 6) STAGE(t + 2, 0, 0),
              (void)0);
        PHASE(t, 1, 1, 0,
              if (t < 6) STAGE(t + 2, 1, 0),
              if (t < 6) { WAITVM(8); } else if (t == 6) { WAITVM(4); });
    }

    // epilogue: per-wave LDS transpose (reuse smem) -> coalesced float4 stores
    asm volatile("" ::: "memory");
    float* sc = (float*)(smem + w * 16 * SCPAD * 4);  // 4352B/wave, disjoint
    int cl = fm, qh = lane >> 4;
    int gcol = n0 + wave_n * 64 + cl * 4;
    float4 bb = bias ? *(const float4*)(bias + gcol)
                     : make_float4(0.f, 0.f, 0.f, 0.f);
#pragma unroll
    for (int i = 0; i < 8; ++i) {
#pragma unroll
        for (int j = 0; j < 4; ++j)
#pragma unroll
            for (int r = 0; r < 4; ++r)
                sc[(qh * 4 + r) * SCPAD + j * 16 + cl] = acc[i][j][r];
#pragma unroll
        for (int rr = 0; rr < 4; ++rr) {
            int lrow = rr * 4 + qh;
            float4 v = *(float4*)(sc + lrow * SCPAD + cl * 4);
            v.x += bb.x; v.y += bb.y; v.z += bb.z; v.w += bb.w;
            *(float4*)(C + (size_t)(m0 + wave_m * 128 + i * 16 + lrow) * ldc + gcol) = v;
        }
    }
}

// ---------------- scan phase 1: gate math + per-chunk affine summary -------
__global__ __launch_bounds__(256) void scan1_k(float* __restrict__ gates,
                                               float* __restrict__ Ach,
                                               float* __restrict__ Bch) {
    int tid = blockIdx.x * blockDim.x + threadIdx.x;
    int ch = tid & (BB * HH - 1);
    int c  = tid >> 10;
    int b = ch >> 9, h = ch & (HH - 1);
    float a = 1.f, acc = 0.f;
    size_t base = ((size_t)b * SS + (size_t)c * CLEN) * G3 + h;
    for (int s = 0; s < CLEN; s++) {
        float fg = gates[base];
        float ig = gates[base + HH];
        float tg = gates[base + 2 * HH];
        float sf = 1.f / (1.f + expf(-fg));
        float si = 1.f / (1.f + expf(-ig));
        float inv = 1.f / (sf + si);
        float fp = sf * inv;
        float ip = si * inv;
        float g  = tg >= 0.f ? tg + 0.5f : 1.f / (1.f + expf(-tg));
        float v  = ip * g;
        gates[base] = fp;
        gates[base + HH] = v;
        a = fp * a;
        acc = fp * acc + v;
        base += G3;
    }
    Ach[tid] = a;
    Bch[tid] = acc;
}

// ---------------- scan phase 2: scan across chunk summaries ---------------
__global__ __launch_bounds__(256) void scan2_k(const float* __restrict__ Ach,
                                               const float* __restrict__ Bch,
                                               float* __restrict__ hin) {
    int ch = blockIdx.x * blockDim.x + threadIdx.x;
    float hh = 0.5f;
    for (int c = 0; c < NCHUNK; c++) {
        int i = c * (BB * HH) + ch;
        hin[i] = hh;
        hh = Ach[i] * hh + Bch[i];
    }
}

// ---------------- scan phase 3: replay chunk, x += h (residual fused) ------
__global__ __launch_bounds__(256) void scan3_k(const float* __restrict__ gates,
                                               const float* __restrict__ hin,
                                               float* __restrict__ x) {
    int tid = blockIdx.x * blockDim.x + threadIdx.x;
    int ch = tid & (BB * HH - 1);
    int c  = tid >> 10;
    int b = ch >> 9, h = ch & (HH - 1);
    float hh = hin[c * (BB * HH) + ch];
    size_t gbase = ((size_t)b * SS + (size_t)c * CLEN) * G3 + h;
    size_t xbase = ((size_t)b * SS + (size_t)c * CLEN) * HH + h;
    for (int s = 0; s < CLEN; s++) {
        float fp = gates[gbase];
        float v  = gates[gbase + HH];
        hh = fp * hh + v;
        x[xbase] += hh;
        gbase += G3;
        xbase += HH;
    }
}

extern "C" void kernel_launch(void* const* d_in, const int* in_sizes, int n_in,
                              void* d_out, int out_size, void* d_ws, size_t ws_size,
                              hipStream_t stream) {
    const int*   ids  = (const int*)  d_in[0];
    const float* emb  = (const float*)d_in[1];
    const float* Ws   = (const float*)d_in[2];
    const float* bs   = (const float*)d_in[3];
    const float* lnw  = (const float*)d_in[4];
    const float* lnb  = (const float*)d_in[5];
    const float* flnw = (const float*)d_in[6];
    const float* fcw  = (const float*)d_in[7];
    const float* fcb  = (const float*)d_in[8];
    float* out = (float*)d_out;

    char* p = (char*)d_ws;
    float* x            = (float*)p;           p += (size_t)ROWS * HH * 4;
    unsigned short* xnb = (unsigned short*)p;  p += (size_t)ROWS * HH * 2;
    unsigned short* wsb = (unsigned short*)p;  p += (size_t)LL * G3 * HH * 2;
    unsigned short* fwb = (unsigned short*)p;  p += (size_t)VV * HH * 2;
    float* gates        = (float*)p;           p += (size_t)ROWS * G3 * 4;
    float* Ach          = (float*)p;           p += (size_t)NCHUNK * BB * HH * 4;
    float* Bch          = (float*)p;           p += (size_t)NCHUNK * BB * HH * 4;
    float* hin          = (float*)p;           p += (size_t)NCHUNK * BB * HH * 4;

    embed_k<<<ROWS * (HH / 4) / 256, 256, 0, stream>>>(ids, emb, x);
    tobf16_k<<<(LL * G3 * HH / 4 + 255) / 256, 256, 0, stream>>>(Ws, wsb, LL * G3 * HH / 4);
    tobf16_k<<<(VV * HH / 4 + 255) / 256, 256, 0, stream>>>(fcw, fwb, VV * HH / 4);

    for (int l = 0; l < LL; l++) {
        ln_k<<<ROWS / 4, 256, 0, stream>>>(x, lnw + l * HH, lnb + l * HH, xnb);
        gemm_bt<<<MT * (G3 / BN), 256, 0, stream>>>(
            xnb, wsb + (size_t)l * G3 * HH, bs + l * G3, gates, HH, G3);
        scan1_k<<<NCHUNK * BB * HH / 256, 256, 0, stream>>>(gates, Ach, Bch);
        scan2_k<<<BB * HH / 256, 256, 0, stream>>>(Ach, Bch, hin);
        scan3_k<<<NCHUNK * BB * HH / 256, 256, 0, stream>>>(gates, hin, x);
    }

    ln_k<<<ROWS / 4, 256, 0, stream>>>(x, flnw, nullptr, xnb);
    gemm256<<<16 * (VV / 256), 512, 0, stream>>>(xnb, fwb, fcb, out, VV);
}

// Round 3
// 922.371 us; speedup vs baseline: 1.5532x; 1.0100x over previous
//
#include <hip/hip_runtime.h>
#include <stdint.h>

// Problem constants (from reference): B=2, S=2048, V=32000, E=H=512, L=3
#define BB 2
#define SS 2048
#define VV 32000
#define HH 512
#define LL 3
#define ROWS (BB * SS)      // 4096
#define G3 (3 * HH)         // 1536

#define NCHUNK 64
#define CLEN (SS / NCHUNK)  // 32

typedef __attribute__((ext_vector_type(8))) __bf16 bf16x8;
typedef __attribute__((ext_vector_type(4))) float f32x4;

// float -> bf16 round-to-nearest-even (bit trick, avoids header dependency)
__device__ __forceinline__ unsigned short f2bf(float f) {
    union { float f; unsigned int u; } cv; cv.f = f;
    unsigned int u = cv.u;
    u += 0x7fffu + ((u >> 16) & 1u);
    return (unsigned short)(u >> 16);
}

// async global->LDS, 16B per lane. LDS dest is wave-uniform base + lane*16 (HW).
__device__ __forceinline__ void gl2lds16(const void* g, void* l) {
    __builtin_amdgcn_global_load_lds(
        (__attribute__((address_space(1))) void*)g,
        (__attribute__((address_space(3))) void*)l, 16, 0, 0);
}

// ---------------- embedding gather: x[row] = emb[ids[row]] ----------------
__global__ __launch_bounds__(256) void embed_k(const int* __restrict__ ids,
                                               const float* __restrict__ emb,
                                               float* __restrict__ x) {
    int idx = blockIdx.x * blockDim.x + threadIdx.x;   // over ROWS * (HH/4)
    int row = idx >> 7;            // HH/4 = 128 float4 per row
    int c4  = idx & 127;
    int id = ids[row];
    *(float4*)(x + (size_t)row * HH + c4 * 4) =
        *(const float4*)(emb + (size_t)id * HH + c4 * 4);
}

// ---------------- fp32 -> bf16 bulk convert ----------------
__global__ __launch_bounds__(256) void tobf16_k(const float* __restrict__ in,
                                                unsigned short* __restrict__ outp,
                                                int n4) {
    int i = blockIdx.x * blockDim.x + threadIdx.x;
    if (i >= n4) return;
    float4 v = *(const float4*)(in + (size_t)i * 4);
    unsigned short o[4] = { f2bf(v.x), f2bf(v.y), f2bf(v.z), f2bf(v.w) };
    *(uint2*)(outp + (size_t)i * 4) = *(uint2*)o;
}

// ---------------- LayerNorm over H=512, one wave per row, writes bf16 ------
__global__ __launch_bounds__(256) void ln_k(const float* __restrict__ x,
                                            const float* __restrict__ w,
                                            const float* __restrict__ b,
                                            unsigned short* __restrict__ xn) {
    int wid  = (blockIdx.x * blockDim.x + threadIdx.x) >> 6;  // global wave = row
    int lane = threadIdx.x & 63;
    if (wid >= ROWS) return;
    const float* xr = x + (size_t)wid * HH;
    float4 v0 = *(const float4*)(xr + lane * 8);
    float4 v1 = *(const float4*)(xr + lane * 8 + 4);
    float vs[8] = { v0.x, v0.y, v0.z, v0.w, v1.x, v1.y, v1.z, v1.w };
    float s = 0.f, q = 0.f;
#pragma unroll
    for (int j = 0; j < 8; j++) { s += vs[j]; q += vs[j] * vs[j]; }
#pragma unroll
    for (int off = 32; off; off >>= 1) {
        s += __shfl_xor(s, off);
        q += __shfl_xor(q, off);
    }
    float mean = s * (1.f / HH);
    float var  = q * (1.f / HH) - mean * mean;
    float r    = rsqrtf(var + 1e-5f);
    unsigned short o[8];
#pragma unroll
    for (int j = 0; j < 8; j++) {
        float wj = w[lane * 8 + j];
        float bj = b ? b[lane * 8 + j] : 0.f;
        o[j] = f2bf((vs[j] - mean) * r * wj + bj);
    }
    *(uint4*)(xn + (size_t)wid * HH + lane * 8) = *(uint4*)o;
}

// ---------------- 128x128 bf16 MFMA GEMM (m97 structure) — layer GEMMs -----
#define BM 128
#define BN 128
#define BK 32
#define MT (ROWS / BM)      // 32 m-tiles
#define SCPAD 68            // epilogue staging row stride (floats)

__global__ __launch_bounds__(256) void gemm_bt(const unsigned short* __restrict__ A,
                                               const unsigned short* __restrict__ Bt,
                                               const float* __restrict__ bias,
                                               float* __restrict__ C,
                                               int K, int ldc) {
    __shared__ __align__(16) char smem[4 * 16 * SCPAD * 4];
    unsigned short* lA = (unsigned short*)smem;
    unsigned short* lB = lA + BM * BK;

    int nwg = gridDim.x;
    int wg = blockIdx.x;
    if ((nwg & 7) == 0) { int q = nwg >> 3; wg = (wg & 7) * q + (wg >> 3); }
    int m0 = (wg % MT) * BM;
    int n0 = (wg / MT) * BN;

    int t = threadIdx.x;
    int lane = t & 63;
    int w = t >> 6;
    int wm = (w >> 1) * 64, wn = (w & 1) * 64;

    f32x4 acc[4][4];
#pragma unroll
    for (int i = 0; i < 4; i++)
#pragma unroll
        for (int j = 0; j < 4; j++) acc[i][j] = (f32x4){0.f, 0.f, 0.f, 0.f};

    int r0 = t >> 2, c0 = (t & 3) * 8;
    const unsigned short* pa0 = A  + (size_t)(m0 + r0) * K + c0;
    const unsigned short* pa1 = A  + (size_t)(m0 + r0 + 64) * K + c0;
    const unsigned short* pb0 = Bt + (size_t)(n0 + r0) * K + c0;
    const unsigned short* pb1 = Bt + (size_t)(n0 + r0 + 64) * K + c0;
    unsigned short* dA0 = lA + (w * 64) * 8;
    unsigned short* dA1 = lA + (256 + w * 64) * 8;
    unsigned short* dB0 = lB + (w * 64) * 8;
    unsigned short* dB1 = lB + (256 + w * 64) * 8;

    int fm = lane & 15;
    int fq = (lane >> 4) * 8;
    const unsigned short* paf = lA + (wm + fm) * BK + fq;
    const unsigned short* pbf = lB + (wn + fm) * BK + fq;

    int nkt = K / BK;
    for (int kt = 0; kt < nkt; kt++) {
        gl2lds16(pa0, dA0);
        gl2lds16(pa1, dA1);
        gl2lds16(pb0, dB0);
        gl2lds16(pb1, dB1);
        pa0 += BK; pa1 += BK; pb0 += BK; pb1 += BK;
        __syncthreads();
        bf16x8 af[4], bfr[4];
#pragma unroll
        for (int i = 0; i < 4; i++) af[i] = *(const bf16x8*)(paf + i * 16 * BK);
#pragma unroll
        for (int j = 0; j < 4; j++) bfr[j] = *(const bf16x8*)(pbf + j * 16 * BK);
#pragma unroll
        for (int i = 0; i < 4; i++)
#pragma unroll
            for (int j = 0; j < 4; j++)
                acc[i][j] = __builtin_amdgcn_mfma_f32_16x16x32_bf16(
                    af[i], bfr[j], acc[i][j], 0, 0, 0);
        __syncthreads();
    }

    float* sc = (float*)(smem + w * 16 * SCPAD * 4);
    int cl = lane & 15, qh = lane >> 4;
    int gcol = n0 + wn + cl * 4;
    float4 bb = bias ? *(const float4*)(bias + gcol)
                     : make_float4(0.f, 0.f, 0.f, 0.f);
#pragma unroll
    for (int i = 0; i < 4; i++) {
#pragma unroll
        for (int j = 0; j < 4; j++)
#pragma unroll
            for (int r = 0; r < 4; r++)
                sc[(qh * 4 + r) * SCPAD + j * 16 + cl] = acc[i][j][r];
#pragma unroll
        for (int rr = 0; rr < 4; rr++) {
            int lrow = rr * 4 + qh;
            float4 v = *(float4*)(sc + lrow * SCPAD + cl * 4);
            v.x += bb.x; v.y += bb.y; v.z += bb.z; v.w += bb.w;
            *(float4*)(C + (size_t)(m0 + wm + i * 16 + lrow) * ldc + gcol) = v;
        }
    }
}

// ================== 256x256 8-phase bf16 GEMM (K=512 fixed) ================
// T3+T4 (8-phase counted vmcnt) + T2 (st_16x32 swizzle) + T5 (setprio).
// 8 waves (2M x 4N), per-wave output 128x64. BK=64 split into kk-halves of 32.
// LDS 128KB: [buf][mat][kk] 16KB regions, double-buffered by K-tile parity.
#define REGION(buf, mat, kk) ((((buf) * 2 + (mat)) * 2 + (kk)) * 16384)
#define WAITVM(n) asm volatile("s_waitcnt vmcnt(" #n ")" ::: "memory")

#define STAGE(tt, mat, kk) do { \
    char* d_ = smem + REGION((tt) & 1, mat, kk) + w * 2048; \
    const unsigned short* s0_ = (mat ? gB0 : gA0) + (tt) * 64 + (kk) * 32; \
    const unsigned short* s1_ = (mat ? gB1 : gA1) + (tt) * 64 + (kk) * 32; \
    gl2lds16(s0_, d_); \
    gl2lds16(s1_, d_ + 1024); \
} while (0)

#define MFMA4(OH, i4, av) do { \
    acc[(OH)*4+(i4)][0] = __builtin_amdgcn_mfma_f32_16x16x32_bf16(av, bq0, acc[(OH)*4+(i4)][0], 0, 0, 0); \
    acc[(OH)*4+(i4)][1] = __builtin_amdgcn_mfma_f32_16x16x32_bf16(av, bq1, acc[(OH)*4+(i4)][1], 0, 0, 0); \
    acc[(OH)*4+(i4)][2] = __builtin_amdgcn_mfma_f32_16x16x32_bf16(av, bq2, acc[(OH)*4+(i4)][2], 0, 0, 0); \
    acc[(OH)*4+(i4)][3] = __builtin_amdgcn_mfma_f32_16x16x32_bf16(av, bq3, acc[(OH)*4+(i4)][3], 0, 0, 0); \
} while (0)

#define PHASE(T, KK, OH, READB, STAGE_STMT, WAIT_STMT) do { \
    const char* Ab_ = smem + REGION((T) & 1, 0, KK) + aoff; \
    const char* Bb_ = smem + REGION((T) & 1, 1, KK) + boff; \
    bf16x8 a0_ = *(const bf16x8*)(Ab_ + ((OH)*4 + 0) * 1024); \
    bf16x8 a1_ = *(const bf16x8*)(Ab_ + ((OH)*4 + 1) * 1024); \
    bf16x8 a2_ = *(const bf16x8*)(Ab_ + ((OH)*4 + 2) * 1024); \
    bf16x8 a3_ = *(const bf16x8*)(Ab_ + ((OH)*4 + 3) * 1024); \
    if (READB) { \
        bq0 = *(const bf16x8*)(Bb_ + 0 * 1024); \
        bq1 = *(const bf16x8*)(Bb_ + 1 * 1024); \
        bq2 = *(const bf16x8*)(Bb_ + 2 * 1024); \
        bq3 = *(const bf16x8*)(Bb_ + 3 * 1024); \
    } \
    STAGE_STMT; \
    WAIT_STMT; \
    __builtin_amdgcn_sched_barrier(0); \
    __builtin_amdgcn_s_barrier(); \
    asm volatile("s_waitcnt lgkmcnt(0)" ::: "memory"); \
    __builtin_amdgcn_sched_barrier(0); \
    __builtin_amdgcn_s_setprio(1); \
    MFMA4(OH, 0, a0_); MFMA4(OH, 1, a1_); MFMA4(OH, 2, a2_); MFMA4(OH, 3, a3_); \
    __builtin_amdgcn_s_setprio(0); \
    __builtin_amdgcn_sched_barrier(0); \
    __builtin_amdgcn_s_barrier(); \
} while (0)

__global__ __launch_bounds__(512, 2) void gemm256(const unsigned short* __restrict__ A,
                                                  const unsigned short* __restrict__ Bt,
                                                  const float* __restrict__ bias,
                                                  float* __restrict__ C, int ldc) {
    __shared__ __align__(16) char smem[131072];

    int nwg = gridDim.x;
    int wg = blockIdx.x;
    if ((nwg & 7) == 0) { int q = nwg >> 3; wg = (wg & 7) * q + (wg >> 3); }
    int m0 = (wg & 15) * 256;          // M = 4096 -> 16 m-tiles, m-fastest
    int n0 = (wg >> 4) * 256;

    int tid = threadIdx.x;
    int lane = tid & 63;
    int w = tid >> 6;
    int wave_m = w >> 2, wave_n = w & 3;

    // fragment lane offset with st_16x32 read swizzle: swz bit = (fm>>3)&1
    int fm = lane & 15;
    int fq16 = (lane >> 4) * 16;
    int lsw = (fm * 64 + fq16) ^ ((fm & 8) ? 32 : 0);
    int aoff = wave_m * 8192 + lsw;
    int boff = wave_n * 4096 + lsw;

    // staging source pre-swizzle (linear LDS dest, inverse-swizzled source)
    int ep = (lane * 8) ^ ((lane & 32) ? 16 : 0);
    int row_l = ep >> 5, kc_l = ep & 31;
    const unsigned short* gA0 = A  + (size_t)(m0 + w * 32 + row_l) * 512 + kc_l;
    const unsigned short* gA1 = gA0 + 16 * 512;
    const unsigned short* gB0 = Bt + (size_t)(n0 + w * 32 + row_l) * 512 + kc_l;
    const unsigned short* gB1 = gB0 + 16 * 512;

    // epilogue constants + bias hoisted above the K-loop (oldest VMEM op;
    // drains at the first counted wait, epilogue starts warm)
    int cl = fm, qh = lane >> 4;
    int gcol = n0 + wave_n * 64 + cl * 4;
    float4 bb = bias ? *(const float4*)(bias + gcol)
                     : make_float4(0.f, 0.f, 0.f, 0.f);

    f32x4 acc[8][4];
#pragma unroll
    for (int i = 0; i < 8; i++)
#pragma unroll
        for (int j = 0; j < 4; j++) acc[i][j] = (f32x4){0.f, 0.f, 0.f, 0.f};
    bf16x8 bq0, bq1, bq2, bq3;

    // prologue
    STAGE(0, 0, 0); STAGE(0, 1, 0); STAGE(0, 0, 1); STAGE(0, 1, 1);
    STAGE(1, 0, 0); STAGE(1, 1, 0);
    WAITVM(8);
    __builtin_amdgcn_sched_barrier(0);
    __builtin_amdgcn_s_barrier();

#pragma unroll
    for (int t = 0; t < 8; ++t) {
        PHASE(t, 0, 0, 1,
              if (t < 7) STAGE(t + 1, 0, 1),
              (void)0);
        PHASE(t, 0, 1, 0,
              if (t < 7) STAGE(t + 1, 1, 1),
              if (t < 7) { WAITVM(8); } else { WAITVM(0); });
        PHASE(t, 1, 0, 1,
              if (t < 6) STAGE(t + 2, 0, 0),
              (void)0);
        PHASE(t, 1, 1, 0,
              if (t < 6) STAGE(t + 2, 1, 0),
              if (t < 6) { WAITVM(8); } else if (t == 6) { WAITVM(4); });
    }

    // epilogue: per-wave LDS transpose (reuse smem) -> coalesced float4 stores
    asm volatile("" ::: "memory");
    float* sc = (float*)(smem + w * 16 * SCPAD * 4);  // 4352B/wave, disjoint
#pragma unroll
    for (int i = 0; i < 8; ++i) {
#pragma unroll
        for (int j = 0; j < 4; ++j)
#pragma unroll
            for (int r = 0; r < 4; ++r)
                sc[(qh * 4 + r) * SCPAD + j * 16 + cl] = acc[i][j][r];
#pragma unroll
        for (int rr = 0; rr < 4; ++rr) {
            int lrow = rr * 4 + qh;
            float4 v = *(float4*)(sc + lrow * SCPAD + cl * 4);
            v.x += bb.x; v.y += bb.y; v.z += bb.z; v.w += bb.w;
            *(float4*)(C + (size_t)(m0 + wave_m * 128 + i * 16 + lrow) * ldc + gcol) = v;
        }
    }
}

// ---------------- scan phase 1: gate math + per-chunk affine summary -------
// Reads gates (const), writes (f',v) to separate restrict fv buffer so the
// compiler can pipeline iteration s+1 loads over iteration s stores.
// fv layout per (b,s) row: [0..HH) = f', [HH..2HH) = v.
__global__ __launch_bounds__(256) void scan1_k(const float* __restrict__ gates,
                                               float* __restrict__ fv,
                                               float* __restrict__ Ach,
                                               float* __restrict__ Bch) {
    int tid = blockIdx.x * blockDim.x + threadIdx.x;
    int ch = tid & (BB * HH - 1);
    int c  = tid >> 10;
    int b = ch >> 9, h = ch & (HH - 1);
    float a = 1.f, acc = 0.f;
    size_t base = ((size_t)b * SS + (size_t)c * CLEN) * G3 + h;
    size_t fvb  = ((size_t)b * SS + (size_t)c * CLEN) * 2 * HH + h;
    for (int s = 0; s < CLEN; s++) {
        float fg = gates[base];
        float ig = gates[base + HH];
        float tg = gates[base + 2 * HH];
        float sf = 1.f / (1.f + expf(-fg));
        float si = 1.f / (1.f + expf(-ig));
        float inv = 1.f / (sf + si);
        float fp = sf * inv;                       // f' = sig(f)/(sig(f)+sig(i))
        float ip = si * inv;
        float g  = tg >= 0.f ? tg + 0.5f : 1.f / (1.f + expf(-tg));
        float v  = ip * g;
        fv[fvb] = fp;
        fv[fvb + HH] = v;
        a = fp * a;
        acc = fp * acc + v;                        // compose h -> fp*h + v
        base += G3;
        fvb += 2 * HH;
    }
    Ach[tid] = a;                                  // layout [c][ch]
    Bch[tid] = acc;
}

// ---------------- scan phase 3: prefix over chunk summaries + replay -------
// scan2 eliminated: each thread computes its chunk-entry state by scanning
// Ach/Bch[cc<c] (coalesced 256B/wave, L2-resident 512KB; <=63 chained FMAs,
// bit-identical order to the old scan2). Then replay + residual.
__global__ __launch_bounds__(256) void scan3_k(const float* __restrict__ fv,
                                               const float* __restrict__ Ach,
                                               const float* __restrict__ Bch,
                                               float* __restrict__ x) {
    int tid = blockIdx.x * blockDim.x + threadIdx.x;
    int ch = tid & (BB * HH - 1);
    int c  = tid >> 10;            // uniform across the block (256 | 1024)
    int b = ch >> 9, h = ch & (HH - 1);
    float hh = 0.5f;               // h0 = g(0) = 0.5
#pragma unroll 4
    for (int cc = 0; cc < c; cc++) {
        int i = cc * (BB * HH) + ch;
        hh = Ach[i] * hh + Bch[i];
    }
    size_t fvb   = ((size_t)b * SS + (size_t)c * CLEN) * 2 * HH + h;
    size_t xbase = ((size_t)b * SS + (size_t)c * CLEN) * HH + h;
    for (int s = 0; s < CLEN; s++) {
        float fp = fv[fvb];
        float v  = fv[fvb + HH];
        hh = fp * hh + v;
        x[xbase] += hh;                               // x = inp + h
        fvb += 2 * HH;
        xbase += HH;
    }
}

extern "C" void kernel_launch(void* const* d_in, const int* in_sizes, int n_in,
                              void* d_out, int out_size, void* d_ws, size_t ws_size,
                              hipStream_t stream) {
    const int*   ids  = (const int*)  d_in[0];
    const float* emb  = (const float*)d_in[1];
    const float* Ws   = (const float*)d_in[2];
    const float* bs   = (const float*)d_in[3];
    const float* lnw  = (const float*)d_in[4];
    const float* lnb  = (const float*)d_in[5];
    const float* flnw = (const float*)d_in[6];
    const float* fcw  = (const float*)d_in[7];
    const float* fcb  = (const float*)d_in[8];
    float* out = (float*)d_out;

    char* p = (char*)d_ws;
    float* x            = (float*)p;           p += (size_t)ROWS * HH * 4;        // 8 MB
    unsigned short* xnb = (unsigned short*)p;  p += (size_t)ROWS * HH * 2;        // 4 MB
    unsigned short* wsb = (unsigned short*)p;  p += (size_t)LL * G3 * HH * 2;     // 4.7 MB
    unsigned short* fwb = (unsigned short*)p;  p += (size_t)VV * HH * 2;          // 32.8 MB
    float* gates        = (float*)p;           p += (size_t)ROWS * G3 * 4;        // 25 MB
    float* fv           = (float*)p;           p += (size_t)ROWS * 2 * HH * 4;    // 16.8 MB
    float* Ach          = (float*)p;           p += (size_t)NCHUNK * BB * HH * 4; // 256 KB
    float* Bch          = (float*)p;           p += (size_t)NCHUNK * BB * HH * 4;

    embed_k<<<ROWS * (HH / 4) / 256, 256, 0, stream>>>(ids, emb, x);
    tobf16_k<<<(LL * G3 * HH / 4 + 255) / 256, 256, 0, stream>>>(Ws, wsb, LL * G3 * HH / 4);
    tobf16_k<<<(VV * HH / 4 + 255) / 256, 256, 0, stream>>>(fcw, fwb, VV * HH / 4);

    for (int l = 0; l < LL; l++) {
        ln_k<<<ROWS / 4, 256, 0, stream>>>(x, lnw + l * HH, lnb + l * HH, xnb);
        gemm_bt<<<MT * (G3 / BN), 256, 0, stream>>>(
            xnb, wsb + (size_t)l * G3 * HH, bs + l * G3, gates, HH, G3);
        scan1_k<<<NCHUNK * BB * HH / 256, 256, 0, stream>>>(gates, fv, Ach, Bch);
        scan3_k<<<NCHUNK * BB * HH / 256, 256, 0, stream>>>(fv, Ach, Bch, x);
    }

    ln_k<<<ROWS / 4, 256, 0, stream>>>(x, flnw, nullptr, xnb);
    gemm256<<<16 * (VV / 256), 512, 0, stream>>>(xnb, fwb, fcb, out, VV);
}